// Round 3
// baseline (390.300 us; speedup 1.0000x reference)
//
#include <hip/hip_runtime.h>
#include <hip/hip_bf16.h>
#include <stdint.h>

// ---------------------------------------------------------------------------
// AnomalyDetector: sample-aggregate -> linear -> softmax -> edge CE(softmax)
// Identity: loss = mean_e( log(sum_v exp(p[src_e,v])) - p[src_e,tgt_e] )
//   with p = softmax(logits);  sum_v exp(p_v) = V + 1 + 0.5*sum(p^2) + O(p^3)
// => need per-node s0 = sum exp(l), q = sum exp(l)^2 (one GEMM pass epilogue)
//
// R3 GEMM structure: A (node features) fully register-resident per wave
// (64 rows x K=256 = 128 VGPR), B streamed through XOR-swizzled
// double-buffered LDS with stage-before-compute (1 barrier per K-step).
// ---------------------------------------------------------------------------

#define NODES 8192
#define DIM   256
#define VOCAB 32768
#define SAMP  10

typedef float  f32x4  __attribute__((ext_vector_type(4)));
typedef short  bf16x8 __attribute__((ext_vector_type(8)));
typedef unsigned short u16x4 __attribute__((ext_vector_type(4)));

static __device__ __forceinline__ unsigned short f2bf(float x) {
    __hip_bfloat16 b = __float2bfloat16(x);
    return *reinterpret_cast<unsigned short*>(&b);
}
static __device__ __forceinline__ float bf2f(unsigned short x) {
    union { unsigned int u; float f; } v; v.u = ((unsigned int)x) << 16; return v.f;
}

// ---------------- K1: neighbor sampling + aggregation ----------------------
__global__ void k_aggregate(const float* __restrict__ z, const float* __restrict__ ru,
                            const int* __restrict__ ptr, const int* __restrict__ col,
                            unsigned short* __restrict__ ub, int nnz) {
    int wid = threadIdx.x >> 6, lane = threadIdx.x & 63;
    int node = blockIdx.x * 4 + wid;
    if (node >= NODES) return;
    int p0 = ptr[node], p1 = ptr[node + 1];
    int deg = p1 - p0;
    float fdeg = (float)deg;
    f32x4 acc = {0.f, 0.f, 0.f, 0.f};
    #pragma unroll
    for (int s = 0; s < SAMP; ++s) {
        float r = ru[node * SAMP + s];
        int samp = (int)(r * fdeg);          // f32 mul + trunc == reference
        int gidx = p0 + samp;
        gidx = gidx < 0 ? 0 : (gidx > nnz - 1 ? nnz - 1 : gidx);
        int nb = (deg > 0) ? col[gidx] : node;
        acc += ((const f32x4*)(z + (size_t)nb * DIM))[lane];
    }
    acc += ((const f32x4*)(z + (size_t)node * DIM))[lane];
    acc = acc / 11.0f;
    u16x4 h;
    h.x = f2bf(acc.x); h.y = f2bf(acc.y); h.z = f2bf(acc.z); h.w = f2bf(acc.w);
    ((u16x4*)(ub + (size_t)node * DIM))[lane] = h;
}

// ---------------- K2: W f32 -> bf16 ---------------------------------------
__global__ void k_convert_w(const float* __restrict__ W, unsigned short* __restrict__ Wb, int n4) {
    int i = blockIdx.x * blockDim.x + threadIdx.x;
    if (i >= n4) return;
    f32x4 v = ((const f32x4*)W)[i];
    u16x4 h;
    h.x = f2bf(v.x); h.y = f2bf(v.y); h.z = f2bf(v.z); h.w = f2bf(v.w);
    ((u16x4*)Wb)[i] = h;
}

// ---------------- K3: reg-A bf16 MFMA GEMM + deferred stats ----------------
#define BM 128
#define BN 256
#define NSTEP 64   // 16 chunks x 4 K-steps

static __device__ __forceinline__ void gload_lds16(const void* g, void* l) {
    __builtin_amdgcn_global_load_lds(
        (const __attribute__((address_space(1))) unsigned int*)g,
        (__attribute__((address_space(3))) unsigned int*)l, 16, 0, 0);
}

__global__ __launch_bounds__(512, 2) void k_gemm_stats(
        const unsigned short* __restrict__ A,   // u_bf [NODES][DIM]
        const unsigned short* __restrict__ B,   // W_bf [VOCAB][DIM]
        float* __restrict__ part_s, float* __restrict__ part_q) {
    // double-buffered B tile [256 rows][64 k-elems], XOR-swizzled slots
    __shared__ __align__(16) unsigned short Bs[2][BN * 64];  // 2 x 32 KB
    __shared__ float sred[BM][4];
    __shared__ float qred[BM][4];

    const int bid = blockIdx.x;
    const int slab = bid & 7;             // XCD-aligned B slab (round-robin)
    const int ntile = bid >> 3;           // 0..63
    const int rm = ntile * BM;
    const int cbase = slab * 4096;
    const int t = threadIdx.x;
    const int lane = t & 63;
    const int wid = t >> 6;               // 8 waves: 2(M) x 4(N)
    const int wr = wid >> 2, wc = wid & 3;
    const int g = lane >> 4, r16 = lane & 15;

    // stage step -> buf. LDS linear dest; GLOBAL source slot pre-swizzled so
    // LDS[row][slot] = G[row][slot ^ (row&7)]  (read applies same XOR).
    auto stage = [&](int buf, int step) {
        const int chunk = step >> 2, ks2 = step & 3;
        const int cn = cbase + chunk * BN;
        #pragma unroll
        for (int i = 0; i < 4; ++i) {
            int idx = i * 512 + t;        // 16B-load index 0..2047
            int row = idx >> 3;           // 0..255
            int sslot = (idx & 7) ^ (row & 7);
            gload_lds16(B + (size_t)(cn + row) * DIM + ks2 * 64 + sslot * 8,
                        (void*)(&Bs[buf][i * 4096 + t * 8]));
        }
    };

    // ---- prologue: stage step 0 + load A fragments to registers ----------
    stage(0, 0);
    bf16x8 areg[4][8];                    // [m][ks*2+kk] : 64 rows x K=256
    #pragma unroll
    for (int m = 0; m < 4; ++m)
        #pragma unroll
        for (int j = 0; j < 8; ++j)
            areg[m][j] = *(const bf16x8*)(A +
                (size_t)(rm + wr * 64 + m * 16 + r16) * DIM + (j * 4 + g) * 8);
    __syncthreads();                      // drains vmcnt(0): stage 0 + A ready

    f32x4 acc[4][4] = {};
    f32x4 sv[4] = {}, qv[4] = {};

    for (int c = 0; c < 16; ++c) {
        #pragma unroll
        for (int ks = 0; ks < 4; ++ks) {  // compile-time ks (areg static idx)
            const int s = c * 4 + ks;
            const int buf = ks & 1;
            if (s + 1 < NSTEP) stage(buf ^ 1, s + 1);   // issue next EARLY
            #pragma unroll
            for (int kk = 0; kk < 2; ++kk) {
                bf16x8 bfr[4];
                #pragma unroll
                for (int n = 0; n < 4; ++n) {
                    int R = wc * 64 + n * 16 + r16;
                    int slot = (kk * 4 + g) ^ (R & 7);
                    bfr[n] = *(const bf16x8*)(&Bs[buf][R * 64 + slot * 8]);
                }
                #pragma unroll
                for (int m = 0; m < 4; ++m)
                    #pragma unroll
                    for (int n = 0; n < 4; ++n)
                        acc[m][n] = __builtin_amdgcn_mfma_f32_16x16x32_bf16(
                            areg[m][ks * 2 + kk], bfr[n], acc[m][n], 0, 0, 0);
            }
            if (ks == 3) {                // fold chunk stats (hides stage lat)
                #pragma unroll
                for (int m = 0; m < 4; ++m)
                    #pragma unroll
                    for (int n = 0; n < 4; ++n) {
                        #pragma unroll
                        for (int reg = 0; reg < 4; ++reg) {
                            float e = __expf(acc[m][n][reg]);
                            sv[m][reg] += e;
                            qv[m][reg] += e * e;
                        }
                        acc[m][n] = (f32x4){0.f, 0.f, 0.f, 0.f};
                    }
            }
            __syncthreads();              // vmcnt(0)+barrier: next buf ready
        }
    }

    // ---- single deferred reduction: over 16 cols (r16 lanes), then wc -----
    #pragma unroll
    for (int m = 0; m < 4; ++m)
        #pragma unroll
        for (int st = 1; st < 16; st <<= 1)
            #pragma unroll
            for (int reg = 0; reg < 4; ++reg) {
                sv[m][reg] += __shfl_xor(sv[m][reg], st, 64);
                qv[m][reg] += __shfl_xor(qv[m][reg], st, 64);
            }
    if (r16 == 0)
        #pragma unroll
        for (int m = 0; m < 4; ++m)
            #pragma unroll
            for (int reg = 0; reg < 4; ++reg) {
                int rl = wr * 64 + m * 16 + g * 4 + reg;
                sred[rl][wc] = sv[m][reg];
                qred[rl][wc] = qv[m][reg];
            }
    __syncthreads();
    if (t < BM) {
        part_s[(size_t)(rm + t) * 8 + slab] = sred[t][0] + sred[t][1] + sred[t][2] + sred[t][3];
        part_q[(size_t)(rm + t) * 8 + slab] = qred[t][0] + qred[t][1] + qred[t][2] + qred[t][3];
    }
}

// ---------------- K4: reduce partials -> s0, lse2 --------------------------
__global__ void k_reduce(const float* __restrict__ part_s, const float* __restrict__ part_q,
                         float* __restrict__ s0, float* __restrict__ lse2) {
    int n = blockIdx.x * 256 + threadIdx.x;
    float s = 0.f, q = 0.f;
    #pragma unroll
    for (int j = 0; j < 8; ++j) { s += part_s[(size_t)n * 8 + j]; q += part_q[(size_t)n * 8 + j]; }
    s0[n] = s;
    lse2[n] = logf((float)VOCAB + 1.0f + 0.5f * q / (s * s));
}

// ---------------- K5: per-edge loss -> per-block partials ------------------
#define ELB 512
__global__ __launch_bounds__(256) void k_edge_loss(
        const unsigned short* __restrict__ ub, const unsigned short* __restrict__ Wb,
        const int* __restrict__ edges, const float* __restrict__ s0,
        const float* __restrict__ lse2, float* __restrict__ partial, int E) {
    int wid = threadIdx.x >> 6, lane = threadIdx.x & 63;
    int w = blockIdx.x * 4 + wid;
    float local = 0.f;
    for (int e = w; e < E; e += ELB * 4) {
        int src = edges[e], tgt = edges[E + e];
        u16x4 a = ((const u16x4*)(ub + (size_t)src * DIM))[lane];
        u16x4 b = ((const u16x4*)(Wb + (size_t)tgt * DIM))[lane];
        float d = bf2f(a.x) * bf2f(b.x) + bf2f(a.y) * bf2f(b.y)
                + bf2f(a.z) * bf2f(b.z) + bf2f(a.w) * bf2f(b.w);
        #pragma unroll
        for (int st = 1; st < 64; st <<= 1) d += __shfl_xor(d, st, 64);
        if (lane == 0) local += lse2[src] - __expf(d) / s0[src];
    }
    __shared__ float bs[4];
    if (lane == 0) bs[wid] = local;
    __syncthreads();
    if (threadIdx.x == 0) partial[blockIdx.x] = bs[0] + bs[1] + bs[2] + bs[3];
}

// ---------------- K6: final scalar reduce ----------------------------------
__global__ void k_final(const float* __restrict__ partial, float* __restrict__ out, float invE) {
    int t = threadIdx.x;                  // 256 threads, 512 partials
    float s = partial[t] + partial[t + 256];
    #pragma unroll
    for (int st = 1; st < 64; st <<= 1) s += __shfl_xor(s, st, 64);
    __shared__ float ls[4];
    if ((t & 63) == 0) ls[t >> 6] = s;
    __syncthreads();
    if (t == 0) out[0] = (ls[0] + ls[1] + ls[2] + ls[3]) * invE;
}

// ---------------------------------------------------------------------------
extern "C" void kernel_launch(void* const* d_in, const int* in_sizes, int n_in,
                              void* d_out, int out_size, void* d_ws, size_t ws_size,
                              hipStream_t stream) {
    const float* z    = (const float*)d_in[0];
    const float* W    = (const float*)d_in[1];
    const float* ru   = (const float*)d_in[2];
    const int* edges  = (const int*)d_in[3];
    const int* ptr    = (const int*)d_in[4];
    const int* col    = (const int*)d_in[5];
    const int E   = in_sizes[3] / 2;
    const int nnz = in_sizes[5];

    char* ws = (char*)d_ws;
    unsigned short* ub     = (unsigned short*)(ws + 0);         //  4 MB
    unsigned short* Wb     = (unsigned short*)(ws + 4194304);   // 16 MB
    float*          part_s = (float*)(ws + 20971520);           // 256 KB
    float*          part_q = (float*)(ws + 21233664);           // 256 KB
    float*          s0     = (float*)(ws + 21495808);           // 32 KB
    float*          lse2   = (float*)(ws + 21528576);           // 32 KB
    float*          epart  = (float*)(ws + 21561344);           //  2 KB
    float*          out    = (float*)d_out;

    hipLaunchKernelGGL(k_aggregate, dim3(NODES / 4), dim3(256), 0, stream, z, ru, ptr, col, ub, nnz);
    hipLaunchKernelGGL(k_convert_w, dim3(VOCAB * DIM / 4 / 256), dim3(256), 0, stream, W, Wb, VOCAB * DIM / 4);
    hipLaunchKernelGGL(k_gemm_stats, dim3(512), dim3(512), 0, stream, ub, Wb, part_s, part_q);
    hipLaunchKernelGGL(k_reduce, dim3(NODES / 256), dim3(256), 0, stream, part_s, part_q, s0, lse2);
    hipLaunchKernelGGL(k_edge_loss, dim3(ELB), dim3(256), 0, stream, ub, Wb, edges, s0, lse2, epart, E);
    hipLaunchKernelGGL(k_final, dim3(1), dim3(256), 0, stream, epart, out, 1.0f / (float)E);
}

// Round 5
// 307.088 us; speedup vs baseline: 1.2710x; 1.2710x over previous
//
#include <hip/hip_runtime.h>
#include <hip/hip_bf16.h>
#include <stdint.h>

// ---------------------------------------------------------------------------
// AnomalyDetector: sample-aggregate -> linear -> softmax -> edge CE(softmax)
// Identity: loss = mean_e( log(sum_v exp(p[src_e,v])) - p[src_e,tgt_e] )
//   sum_v exp(p_v) = V + 1 + 0.5*sum(p^2)+...;  sum(p^2) ~ 3e-5 vanishes in
//   f32 at 32769 (ulp=0.0039) => lse2 == logf(V+1) EXACTLY in f32.
// => GEMM epilogue only needs s0[n] = sum_v exp(logit) (softmax denominator)
//
// GEMM: A reg-resident (wave=32 rows x K=256 = 64 VGPR), B streamed through
// XOR-swizzled double-buffered LDS, stage-before-compute, 1 barrier/step.
// 8 waves = 4M x 2N; ~190 VGPR -> 2 waves/SIMD, no spill (bounds (512,1)).
// ---------------------------------------------------------------------------

#define NODES 8192
#define DIM   256
#define VOCAB 32768
#define SAMP  10

typedef float  f32x4  __attribute__((ext_vector_type(4)));
typedef short  bf16x8 __attribute__((ext_vector_type(8)));
typedef unsigned short u16x4 __attribute__((ext_vector_type(4)));

static __device__ __forceinline__ unsigned short f2bf(float x) {
    __hip_bfloat16 b = __float2bfloat16(x);
    return *reinterpret_cast<unsigned short*>(&b);
}
static __device__ __forceinline__ float bf2f(unsigned short x) {
    union { unsigned int u; float f; } v; v.u = ((unsigned int)x) << 16; return v.f;
}

// ---------------- K1: neighbor sampling + aggregation ----------------------
__global__ void k_aggregate(const float* __restrict__ z, const float* __restrict__ ru,
                            const int* __restrict__ ptr, const int* __restrict__ col,
                            unsigned short* __restrict__ ub, int nnz) {
    int wid = threadIdx.x >> 6, lane = threadIdx.x & 63;
    int node = blockIdx.x * 4 + wid;
    if (node >= NODES) return;
    int p0 = ptr[node], p1 = ptr[node + 1];
    int deg = p1 - p0;
    float fdeg = (float)deg;
    f32x4 acc = {0.f, 0.f, 0.f, 0.f};
    #pragma unroll
    for (int s = 0; s < SAMP; ++s) {
        float r = ru[node * SAMP + s];
        int samp = (int)(r * fdeg);          // f32 mul + trunc == reference
        int gidx = p0 + samp;
        gidx = gidx < 0 ? 0 : (gidx > nnz - 1 ? nnz - 1 : gidx);
        int nb = (deg > 0) ? col[gidx] : node;
        acc += ((const f32x4*)(z + (size_t)nb * DIM))[lane];
    }
    acc += ((const f32x4*)(z + (size_t)node * DIM))[lane];
    acc = acc / 11.0f;
    u16x4 h;
    h.x = f2bf(acc.x); h.y = f2bf(acc.y); h.z = f2bf(acc.z); h.w = f2bf(acc.w);
    ((u16x4*)(ub + (size_t)node * DIM))[lane] = h;
}

// ---------------- K2: W f32 -> bf16 ---------------------------------------
__global__ void k_convert_w(const float* __restrict__ W, unsigned short* __restrict__ Wb, int n4) {
    int i = blockIdx.x * blockDim.x + threadIdx.x;
    if (i >= n4) return;
    f32x4 v = ((const f32x4*)W)[i];
    u16x4 h;
    h.x = f2bf(v.x); h.y = f2bf(v.y); h.z = f2bf(v.z); h.w = f2bf(v.w);
    ((u16x4*)Wb)[i] = h;
}

// ---------------- K3: reg-A bf16 MFMA GEMM + s0 epilogue -------------------
#define BM 128
#define BN 256
#define NSTEP 64   // 16 chunks x 4 K-steps

static __device__ __forceinline__ void gload_lds16(const void* g, void* l) {
    __builtin_amdgcn_global_load_lds(
        (const __attribute__((address_space(1))) unsigned int*)g,
        (__attribute__((address_space(3))) unsigned int*)l, 16, 0, 0);
}

__global__ __launch_bounds__(512, 1) void k_gemm_stats(
        const unsigned short* __restrict__ A,   // u_bf [NODES][DIM]
        const unsigned short* __restrict__ B,   // W_bf [VOCAB][DIM]
        float* __restrict__ part_s) {
    // double-buffered B tile [256 rows][64 k-elems], XOR-swizzled slots
    __shared__ __align__(16) unsigned short Bs[2][BN * 64];  // 2 x 32 KB
    __shared__ float sred[BM][2];

    const int bid = blockIdx.x;
    const int slab = bid & 7;             // XCD-aligned B slab (round-robin)
    const int ntile = bid >> 3;           // 0..63
    const int rm = ntile * BM;
    const int cbase = slab * 4096;
    const int t = threadIdx.x;
    const int lane = t & 63;
    const int wid = t >> 6;               // 8 waves: 4(M) x 2(N)
    const int wr = wid >> 1, wc = wid & 1;
    const int g = lane >> 4, r16 = lane & 15;

    // stage step -> buf. LDS linear dest; GLOBAL source slot pre-swizzled so
    // LDS[row][slot] = G[row][slot ^ (row&7)]  (read applies same XOR).
    auto stage = [&](int buf, int step) {
        const int chunk = step >> 2, ks2 = step & 3;
        const int cn = cbase + chunk * BN;
        #pragma unroll
        for (int i = 0; i < 4; ++i) {
            int idx = i * 512 + t;        // 16B-load index 0..2047
            int row = idx >> 3;           // 0..255
            int sslot = (idx & 7) ^ (row & 7);
            gload_lds16(B + (size_t)(cn + row) * DIM + ks2 * 64 + sslot * 8,
                        (void*)(&Bs[buf][i * 4096 + t * 8]));
        }
    };

    // ---- prologue: stage step 0 + load A fragments to registers ----------
    stage(0, 0);
    bf16x8 areg[2][8];                    // [m][ks*2+kk] : 32 rows x K=256
    #pragma unroll
    for (int m = 0; m < 2; ++m)
        #pragma unroll
        for (int j = 0; j < 8; ++j)
            areg[m][j] = *(const bf16x8*)(A +
                (size_t)(rm + wr * 32 + m * 16 + r16) * DIM + (j * 4 + g) * 8);
    __syncthreads();                      // drains vmcnt(0): stage 0 + A ready

    f32x4 acc[2][8] = {};
    f32x4 sv[2] = {};

    for (int c = 0; c < 16; ++c) {
        #pragma unroll
        for (int ks = 0; ks < 4; ++ks) {  // compile-time ks (areg static idx)
            const int s = c * 4 + ks;
            const int buf = ks & 1;
            if (s + 1 < NSTEP) stage(buf ^ 1, s + 1);   // issue next EARLY
            #pragma unroll
            for (int kk = 0; kk < 2; ++kk) {
                bf16x8 bfr[8];
                #pragma unroll
                for (int n = 0; n < 8; ++n) {
                    int R = wc * 128 + n * 16 + r16;
                    int slot = (kk * 4 + g) ^ (R & 7);
                    bfr[n] = *(const bf16x8*)(&Bs[buf][R * 64 + slot * 8]);
                }
                #pragma unroll
                for (int m = 0; m < 2; ++m)
                    #pragma unroll
                    for (int n = 0; n < 8; ++n)
                        acc[m][n] = __builtin_amdgcn_mfma_f32_16x16x32_bf16(
                            areg[m][ks * 2 + kk], bfr[n], acc[m][n], 0, 0, 0);
            }
            if (ks == 3) {                // fold chunk stats (hides stage lat)
                #pragma unroll
                for (int m = 0; m < 2; ++m)
                    #pragma unroll
                    for (int n = 0; n < 8; ++n) {
                        #pragma unroll
                        for (int reg = 0; reg < 4; ++reg)
                            sv[m][reg] += __expf(acc[m][n][reg]);
                        acc[m][n] = (f32x4){0.f, 0.f, 0.f, 0.f};
                    }
            }
            __syncthreads();              // vmcnt(0)+barrier: next buf ready
        }
    }

    // ---- single deferred reduction: 16 cols per lane-group, then wc -------
    #pragma unroll
    for (int m = 0; m < 2; ++m)
        #pragma unroll
        for (int st = 1; st < 16; st <<= 1)
            #pragma unroll
            for (int reg = 0; reg < 4; ++reg)
                sv[m][reg] += __shfl_xor(sv[m][reg], st, 64);
    if (r16 == 0)
        #pragma unroll
        for (int m = 0; m < 2; ++m)
            #pragma unroll
            for (int reg = 0; reg < 4; ++reg)
                sred[wr * 32 + m * 16 + g * 4 + reg][wc] = sv[m][reg];
    __syncthreads();
    if (t < BM)
        part_s[(size_t)(rm + t) * 8 + slab] = sred[t][0] + sred[t][1];
}

// ---------------- K4: reduce partials -> s0 --------------------------------
__global__ void k_reduce(const float* __restrict__ part_s, float* __restrict__ s0) {
    int n = blockIdx.x * 256 + threadIdx.x;
    float s = 0.f;
    #pragma unroll
    for (int j = 0; j < 8; ++j) s += part_s[(size_t)n * 8 + j];
    s0[n] = s;
}

// ---------------- K5: per-edge loss -> per-block partials ------------------
#define ELB 512
__global__ __launch_bounds__(256) void k_edge_loss(
        const unsigned short* __restrict__ ub, const unsigned short* __restrict__ Wb,
        const int* __restrict__ edges, const float* __restrict__ s0,
        float lse2c, float* __restrict__ partial, int E) {
    int wid = threadIdx.x >> 6, lane = threadIdx.x & 63;
    int w = blockIdx.x * 4 + wid;
    float local = 0.f;
    for (int e = w; e < E; e += ELB * 4) {
        int src = edges[e], tgt = edges[E + e];
        u16x4 a = ((const u16x4*)(ub + (size_t)src * DIM))[lane];
        u16x4 b = ((const u16x4*)(Wb + (size_t)tgt * DIM))[lane];
        float d = bf2f(a.x) * bf2f(b.x) + bf2f(a.y) * bf2f(b.y)
                + bf2f(a.z) * bf2f(b.z) + bf2f(a.w) * bf2f(b.w);
        #pragma unroll
        for (int st = 1; st < 64; st <<= 1) d += __shfl_xor(d, st, 64);
        if (lane == 0) local += lse2c - __expf(d) / s0[src];
    }
    __shared__ float bs[4];
    if (lane == 0) bs[wid] = local;
    __syncthreads();
    if (threadIdx.x == 0) partial[blockIdx.x] = bs[0] + bs[1] + bs[2] + bs[3];
}

// ---------------- K6: final scalar reduce ----------------------------------
__global__ void k_final(const float* __restrict__ partial, float* __restrict__ out, float invE) {
    int t = threadIdx.x;                  // 256 threads, 512 partials
    float s = partial[t] + partial[t + 256];
    #pragma unroll
    for (int st = 1; st < 64; st <<= 1) s += __shfl_xor(s, st, 64);
    __shared__ float ls[4];
    if ((t & 63) == 0) ls[t >> 6] = s;
    __syncthreads();
    if (t == 0) out[0] = (ls[0] + ls[1] + ls[2] + ls[3]) * invE;
}

// ---------------------------------------------------------------------------
extern "C" void kernel_launch(void* const* d_in, const int* in_sizes, int n_in,
                              void* d_out, int out_size, void* d_ws, size_t ws_size,
                              hipStream_t stream) {
    const float* z    = (const float*)d_in[0];
    const float* W    = (const float*)d_in[1];
    const float* ru   = (const float*)d_in[2];
    const int* edges  = (const int*)d_in[3];
    const int* ptr    = (const int*)d_in[4];
    const int* col    = (const int*)d_in[5];
    const int E   = in_sizes[3] / 2;
    const int nnz = in_sizes[5];

    char* ws = (char*)d_ws;
    unsigned short* ub     = (unsigned short*)(ws + 0);         //  4 MB
    unsigned short* Wb     = (unsigned short*)(ws + 4194304);   // 16 MB
    float*          part_s = (float*)(ws + 20971520);           // 256 KB
    float*          s0     = (float*)(ws + 21233664);           // 32 KB
    float*          epart  = (float*)(ws + 21266432);           //  2 KB
    float*          out    = (float*)d_out;

    const float lse2c = logf((float)VOCAB + 1.0f);  // == f32 of log(V+1+0.5*sum p^2)

    hipLaunchKernelGGL(k_aggregate, dim3(NODES / 4), dim3(256), 0, stream, z, ru, ptr, col, ub, nnz);
    hipLaunchKernelGGL(k_convert_w, dim3(VOCAB * DIM / 4 / 256), dim3(256), 0, stream, W, Wb, VOCAB * DIM / 4);
    hipLaunchKernelGGL(k_gemm_stats, dim3(512), dim3(512), 0, stream, ub, Wb, part_s);
    hipLaunchKernelGGL(k_reduce, dim3(NODES / 256), dim3(256), 0, stream, part_s, s0);
    hipLaunchKernelGGL(k_edge_loss, dim3(ELB), dim3(256), 0, stream, ub, Wb, edges, s0, lse2c, epart, E);
    hipLaunchKernelGGL(k_final, dim3(1), dim3(256), 0, stream, epart, out, 1.0f / (float)E);
}